// Round 2
// 99.951 us; speedup vs baseline: 1.0141x; 1.0141x over previous
//
#include <hip/hip_runtime.h>
#include <cstdint>
#include <cstddef>

// Problem constants (PairwiseConv_22488448761917)
#define BATCH   4
#define CIN     128
#define NN      4096
#define EE      131072
#define CCONV   127      // C_OUT - 1
#define NBC     512      // B*C elements per node row in (N,B,C) layout
#define MAXDEG  128      // ELL row capacity; deg ~ Bin(131072,1/4096), P(>128) ~ e^-81
#define CPAD    16       // counter padding: one int per 64B cacheline

typedef __attribute__((ext_vector_type(8))) short short8;            // 8 fp16 bits
typedef __attribute__((ext_vector_type(8))) unsigned short ushort8;  // 8 fp16 bits
typedef __attribute__((ext_vector_type(8))) _Float16 half8;          // 8 fp16 (4 VGPRs)
typedef __attribute__((ext_vector_type(4))) float f32x4;             // MFMA C/D frag + NT vec

__device__ __forceinline__ unsigned short f2h(float f) {
    _Float16 h = (_Float16)f;
    return __builtin_bit_cast(unsigned short, h);
}

// ---------------------------------------------------------------------------
// K1 (fused pre):
//   blocks [0,256)   : transpose x (B,C,N) fp32 -> xT (N,B,C) fp16.
//     fp16 (not bf16): enables v_pk_add_f16 accumulate in K2 Phase A and
//     carries 3 more mantissa bits. x reads nontemporal (streamed once) so
//     the xT writes, not the x stream, own L2 when K2 starts gathering.
//   blocks [256,768) : ELL build: elist[ni*128+pos]=nj; padded-counter atomics.
//   blocks [768,896) : WTb[o][k] fp16 weight repack.
// ---------------------------------------------------------------------------
__global__ __launch_bounds__(256) void k_pre(const float* __restrict__ x,
                                             unsigned short* __restrict__ xT,
                                             const float* __restrict__ W,
                                             unsigned short* __restrict__ WTb,
                                             const int* __restrict__ idx_i,
                                             const int* __restrict__ idx_j,
                                             int* __restrict__ cursor,
                                             unsigned short* __restrict__ elist,
                                             int* __restrict__ deg) {
    const int bid = blockIdx.x;
    const int tid = threadIdx.x;
    if (bid < 256) {
        __shared__ float tile[128][65];
        const int b  = bid & 3;
        const int n0 = (bid >> 2) * 64;
        // read: 128 c-rows x 64 floats; 16 rows x 16 lanes(float4) per iter
        const int rl = tid >> 4;       // row within group (0..15)
        const int l4 = (tid & 15) * 4; // float4 offset within row
        const float* xb = x + (size_t)b * CIN * NN + n0 + l4;
#pragma unroll
        for (int it = 0; it < 8; ++it) {
            const int c = it * 16 + rl;
            const f32x4 v = __builtin_nontemporal_load((const f32x4*)(xb + (size_t)c * NN));
            tile[c][l4 + 0] = v[0];
            tile[c][l4 + 1] = v[1];
            tile[c][l4 + 2] = v[2];
            tile[c][l4 + 3] = v[3];
        }
        __syncthreads();
        // write: 64 node-rows x 256 B; 4 nodes x 64 lanes(ushort2) per iter
        const int l = tid & 63;
#pragma unroll
        for (int it = 0; it < 16; ++it) {
            const int n = it * 4 + (tid >> 6);
            ushort2 r;
            r.x = f2h(tile[2 * l + 0][n]);
            r.y = f2h(tile[2 * l + 1][n]);
            *(ushort2*)(xT + (size_t)(n0 + n) * NBC + b * CIN + 2 * l) = r;
        }
    } else if (bid < 768) {
        const int e  = (bid - 256) * 256 + tid;
        const int ni = idx_i[e];
        const int nj = idx_j[e];
        const int pos = atomicAdd(&cursor[ni * CPAD], 1);
        elist[(size_t)ni * MAXDEG + pos] = (unsigned short)nj;
        atomicAdd(&deg[nj * CPAD], 1);
    } else {
        const int t = (bid - 768) * 256 + tid;    // < 128*256
        const int o = t >> 8;
        const int k = t & 255;
        float v = 0.0f;
        if (o < CCONV) v = W[((size_t)o * CIN + (k & 127)) * 2 + (k >> 7)];
        WTb[t] = f2h(v);
    }
}

// ---------------------------------------------------------------------------
// K2 (final, fused gather-agg + MFMA GEMM + epilogue):
//   Block = (16-node tile) x (batch b); grid 256x4 = 1024 blocks (4/CU).
//   Phase A: gather-agg, 2-deep software pipeline (next index vector + next
//     8 gathers prefetched while current group accumulates in packed fp16
//     via v_pk_add_f16 — 4x fewer VALU instrs than the bf16 cvt+add path).
//     Speculative elist reads stay inside the 128-entry row (deg << 128);
//     speculative index VALUES are only used on iterations where k+8<=dn.
//     A-frag pack is now a free bitcast (acc already fp16).
//   Phase B: x-part (kt 0..3): Z = xT * cnt in packed fp16.
//   Phase C: MFMA 16x16x32 f16: M=16(j) x N=128(o) x K=256.
//     B from global WTb[o][k] (64 KB, L2-hot).
//     D layout (m89): col(o)=lane&15, row(j)=(lane>>4)*4+reg.
//   Phase D: epilogue (cnt*bias, /deg) + ch127 = deg row. NONTEMPORAL stores
//     so the 8 MB f32 output stream does not evict the 4 MB xT gather table
//     from per-XCD L2.
// ---------------------------------------------------------------------------
__global__ __launch_bounds__(256) void k_final(const unsigned short* __restrict__ xT,
                                               const unsigned short* __restrict__ WTb,
                                               const float* __restrict__ bias,
                                               const unsigned short* __restrict__ elist,
                                               const int* __restrict__ cnt_i,
                                               const int* __restrict__ deg,
                                               float* __restrict__ out) {
    __shared__ __align__(16) short Af[512 * 8];   // 8 KB: 8 kt x 64 lane x 16 B
    __shared__ float cntf[16], invd[16], degf[16], biasf[128];
    __shared__ int   cnti[16];

    const int tid = threadIdx.x;
    const int b   = blockIdx.y;
    const int n0  = blockIdx.x * 16;

    if (tid < 16) {
        const int c = cnt_i[(n0 + tid) * CPAD];
        const int d = deg[(n0 + tid) * CPAD];
        cnti[tid] = c;
        cntf[tid] = (float)c;
        degf[tid] = (float)d;
        invd[tid] = (d == 0) ? 1.0f : 1.0f / (float)d;
    } else if (tid >= 64 && tid < 192) {
        const int o = tid - 64;
        biasf[o] = (o < CCONV) ? bias[o] : 0.0f;
    }
    __syncthreads();

    const int lane = tid & 63;
    const int w    = tid >> 6;

    // ---- Phase A: pipelined gather-agg -> A-frag slots kt 4..7 ----
    {
        const int ns = lane >> 4;           // node within wave's group of 4
        const int j  = w * 4 + ns;          // 0..15
        const int c0 = (lane & 15) * 8;     // channel base (8 ch per lane)
        const unsigned short* xb = xT + b * CIN + c0;
        const int dn = cnti[j];
        const unsigned short* erow = elist + (size_t)(n0 + j) * MAXDEG;
        half8 accA = {0, 0, 0, 0, 0, 0, 0, 0};
        half8 accB = {0, 0, 0, 0, 0, 0, 0, 0};
        int k = 0;
        if (dn >= 8) {
            ushort8 idx  = *(const ushort8*)(erow);       // edges [0,8) -- valid
            ushort8 idxn = *(const ushort8*)(erow + 8);   // speculative, in-row safe
            half8 u[8];
#pragma unroll
            for (int t = 0; t < 8; ++t)
                u[t] = *(const half8*)(xb + (size_t)idx[t] * NBC);
            for (k = 8; k + 8 <= dn; k += 8) {
                // idxn holds edges [k,k+8): valid here (k+8<=dn). Issue next
                // gathers first so their latency hides under the accumulate.
                half8 un[8];
#pragma unroll
                for (int t = 0; t < 8; ++t)
                    un[t] = *(const half8*)(xb + (size_t)idxn[t] * NBC);
                idxn = *(const ushort8*)(erow + k + 8);   // speculative prefetch
#pragma unroll
                for (int t = 0; t < 8; t += 2) {          // two chains: break dep
                    accA += u[t];
                    accB += u[t + 1];
                }
#pragma unroll
                for (int t = 0; t < 8; ++t) u[t] = un[t];
            }
#pragma unroll
            for (int t = 0; t < 8; t += 2) {              // drain last group
                accA += u[t];
                accB += u[t + 1];
            }
        }
        for (; k < dn; ++k)
            accA += *(const half8*)(xb + (size_t)erow[k] * NBC);
        const half8 s = accA + accB;
        const int kt   = 4 + (c0 >> 5);
        const int g    = (c0 >> 3) & 3;
        const int unit = kt * 64 + 16 * g + j;
        *(half8*)&Af[unit * 8] = s;
    }

    // ---- Phase B: x-part staging (kt 0..3), 256 units / 256 threads ----
    {
        const int L  = tid & 63;
        const int kt = tid >> 6;            // 0..3
        const int j  = L & 15;
        const int k0 = kt * 32 + (L >> 4) * 8;
        const half8 a = *(const half8*)(xT + (size_t)(n0 + j) * NBC + b * CIN + k0);
        const _Float16 sc = (_Float16)cntf[j];
        const half8 p = a * sc;
        *(half8*)&Af[(kt * 64 + L) * 8] = p;
    }
    __syncthreads();

    // ---- Phase C: MFMA (fp16 operands, f32 accum) ----
    const int m = lane & 15;
    const int g = lane >> 4;

    f32x4 acc0 = (f32x4){0.0f, 0.0f, 0.0f, 0.0f};
    f32x4 acc1 = (f32x4){0.0f, 0.0f, 0.0f, 0.0f};

    const unsigned short* B0 = WTb + (size_t)(w * 32 + m) * 256;
    const unsigned short* B1 = B0 + 16 * 256;

#pragma unroll
    for (int kt = 0; kt < 8; ++kt) {
        const int k0 = kt * 32 + g * 8;
        const half8 b0 = *(const half8*)(B0 + k0);
        const half8 b1 = *(const half8*)(B1 + k0);
        const half8 a  = *(const half8*)&Af[(kt * 64 + lane) * 8];
        acc0 = __builtin_amdgcn_mfma_f32_16x16x32_f16(a, b0, acc0, 0, 0, 0);
        acc1 = __builtin_amdgcn_mfma_f32_16x16x32_f16(a, b1, acc1, 0, 0, 0);
    }

    // ---- Phase D: epilogue (nontemporal: keep xT resident in L2) ----
#pragma unroll
    for (int nt = 0; nt < 2; ++nt) {
        const f32x4 a = nt ? acc1 : acc0;
        const int o = w * 32 + nt * 16 + m;
        if (o >= CCONV) continue;   // o==127 handled below
        const float bo = biasf[o];
        float* orow = out + ((size_t)b * 128 + o) * NN + n0;
        const int j0 = g * 4;
        f32x4 r;
        r[0] = (a[0] + cntf[j0 + 0] * bo) * invd[j0 + 0];
        r[1] = (a[1] + cntf[j0 + 1] * bo) * invd[j0 + 1];
        r[2] = (a[2] + cntf[j0 + 2] * bo) * invd[j0 + 2];
        r[3] = (a[3] + cntf[j0 + 3] * bo) * invd[j0 + 3];
        __builtin_nontemporal_store(r, (f32x4*)(orow + j0));
    }
    // fused ch127: out[b][127][n] = deg[n]
    if (tid < 16)
        __builtin_nontemporal_store(degf[tid],
                                    &out[((size_t)b * 128 + CCONV) * NN + n0 + tid]);
}

// ---------------------------------------------------------------------------
extern "C" void kernel_launch(void* const* d_in, const int* in_sizes, int n_in,
                              void* d_out, int out_size, void* d_ws, size_t ws_size,
                              hipStream_t stream) {
    const float* x    = (const float*)d_in[0];
    const float* W    = (const float*)d_in[1];
    const float* bias = (const float*)d_in[2];
    const int* idx_i  = (const int*)d_in[3];
    const int* idx_j  = (const int*)d_in[4];
    float* out = (float*)d_out;

    // Workspace layout (bytes):
    //   xT     : 0        (+4194304)   fp16 (N,B,C)
    //   elist  : 4194304  (+1048576)   ushort[N][128] ELL
    //   WTb    : 5242880  (+65536)     fp16[128][256]
    //   cursor : 5308416  (+262144)    int[N*16] padded (becomes cnt_i)
    //   deg    : 5570560  (+262144)    int[N*16] padded  -> end 5832704
    char* ws = (char*)d_ws;
    unsigned short* xT     = (unsigned short*)(ws);
    unsigned short* elist  = (unsigned short*)(ws + 4194304);
    unsigned short* WTb    = (unsigned short*)(ws + 5242880);
    int*            cursor = (int*)(ws + 5308416);
    int*            deg    = (int*)(ws + 5570560);

    // Zero cursor + deg (contiguous 512 KB)
    (void)hipMemsetAsync(cursor, 0, 524288, stream);

    k_pre<<<896, 256, 0, stream>>>(x, xT, W, WTb, idx_i, idx_j, cursor, elist, deg);
    k_final<<<dim3(NN / 16, BATCH), 256, 0, stream>>>(xT, WTb, bias, elist, cursor, deg, out);
}